// Round 12
// baseline (334.001 us; speedup 1.0000x reference)
//
#include <hip/hip_runtime.h>

#define BB 16
#define SS 512
#define KIN 512
#define H 256

typedef float v2f __attribute__((ext_vector_type(2)));

constexpr float DECAY = 0.951229424500714f;    // exp(-1/20), both tau=20
constexpr float OMD   = 0.048770575499286f;    // 1 - exp(-1/20)
constexpr float LR    = 0.01f;

__device__ __forceinline__ float fast_tanh(float x) {
    float e = __expf(2.f * x);
    return 1.f - __fdividef(2.f, e + 1.f);
}

__device__ __forceinline__ v2f pk_mul(v2f a, v2f b) {
    v2f d; asm("v_pk_mul_f32 %0, %1, %2" : "=v"(d) : "v"(a), "v"(b)); return d;
}
__device__ __forceinline__ v2f pk_fma(v2f a, v2f b, v2f c) {
    v2f d; asm("v_pk_fma_f32 %0, %1, %2, %3" : "=v"(d) : "v"(a), "v"(b), "v"(c)); return d;
}

// Per-32-half allreduce (R10-VERIFIED): 4x DPP row_shr prefix + row_bcast15
// (rows 1,3) puts half sums in lanes 31/63; ds_swizzle 0x3E0 (src = lane 31
// of each 32-group) broadcasts each half's own sum to all its lanes.
__device__ __forceinline__ float allred32(float x) {
    int t;
    t = __builtin_amdgcn_update_dpp(0, __float_as_int(x), 0x111, 0xf, 0xf, false);
    x += __int_as_float(t);
    t = __builtin_amdgcn_update_dpp(0, __float_as_int(x), 0x112, 0xf, 0xf, false);
    x += __int_as_float(t);
    t = __builtin_amdgcn_update_dpp(0, __float_as_int(x), 0x114, 0xf, 0xf, false);
    x += __int_as_float(t);
    t = __builtin_amdgcn_update_dpp(0, __float_as_int(x), 0x118, 0xf, 0xf, false);
    x += __int_as_float(t);
    t = __builtin_amdgcn_update_dpp(0, __float_as_int(x), 0x142, 0xa, 0xf, false);
    x += __int_as_float(t);
    return __int_as_float(__builtin_amdgcn_ds_swizzle(__float_as_int(x), 0x3E0));
}

// i = x @ W^T. ik half (n<256) -> ik_out[b*512+s][256]; iv half -> iv_t[b][row][s].
__global__ __launch_bounds__(256) void gemm_xwT(const float* __restrict__ X,
                                                const float* __restrict__ W,
                                                float* __restrict__ ik_out,
                                                float* __restrict__ iv_t) {
    __shared__ float As[16][68];
    __shared__ float Bs[16][68];
    const int m0 = blockIdx.y * 64;
    const int n0 = blockIdx.x * 64;
    const int tid = threadIdx.x;
    const int r  = tid >> 2;
    const int cg = tid & 3;
    const int tx = tid & 15;
    const int ty = tid >> 4;
    float acc[4][4] = {};
    for (int k0 = 0; k0 < KIN; k0 += 16) {
        float4 av = *(const float4*)&X[(size_t)(m0 + r) * KIN + k0 + cg * 4];
        float4 bv = *(const float4*)&W[(size_t)(n0 + r) * KIN + k0 + cg * 4];
        __syncthreads();
        As[cg*4+0][r] = av.x; As[cg*4+1][r] = av.y; As[cg*4+2][r] = av.z; As[cg*4+3][r] = av.w;
        Bs[cg*4+0][r] = bv.x; Bs[cg*4+1][r] = bv.y; Bs[cg*4+2][r] = bv.z; Bs[cg*4+3][r] = bv.w;
        __syncthreads();
#pragma unroll
        for (int kk = 0; kk < 16; ++kk) {
            float4 a = *(const float4*)&As[kk][ty * 4];
            float4 b = *(const float4*)&Bs[kk][tx * 4];
            float ar[4] = {a.x, a.y, a.z, a.w};
            float br[4] = {b.x, b.y, b.z, b.w};
#pragma unroll
            for (int i = 0; i < 4; ++i)
#pragma unroll
                for (int j = 0; j < 4; ++j) acc[i][j] += ar[i] * br[j];
        }
    }
    if (n0 < 256) {
#pragma unroll
        for (int i = 0; i < 4; ++i) {
            float4 o = make_float4(acc[i][0], acc[i][1], acc[i][2], acc[i][3]);
            *(float4*)&ik_out[(size_t)(m0 + ty * 4 + i) * 256 + n0 + tx * 4] = o;
        }
    } else {
        const int b  = m0 >> 9;
        const int s0 = (m0 & 511) + ty * 4;
#pragma unroll
        for (int j = 0; j < 4; ++j) {
            float4 o = make_float4(acc[0][j], acc[1][j], acc[2][j], acc[3][j]);
            *(float4*)&iv_t[((size_t)b * H + (n0 - 256 + tx * 4 + j)) * SS + s0] = o;
        }
    }
}

// Per (b, col): scan kv; write key to output and kt in-place over ik.
__global__ __launch_bounds__(64) void key_scan(float* ik,
                                               float* __restrict__ keys) {
    const int idx = blockIdx.x * 64 + threadIdx.x;   // 0..4095
    const int b   = idx >> 8;
    const int col = idx & 255;
    float* c  = ik + (size_t)b * SS * 256 + col;
    float* ko = keys + (size_t)b * SS * H + col;
    float kv = 0.f, kt = 0.f;
    constexpr int D = 32;
    float ib[D];
#pragma unroll
    for (int j = 0; j < D; ++j) ib[j] = c[(size_t)j * 256];
    for (int t = 0; t < SS; t += D) {
#pragma unroll
        for (int j = 0; j < D; ++j) {
            float v = ib[j];
            int tn = t + D + j; if (tn > SS - 1) tn = SS - 1;
            ib[j] = c[(size_t)tn * 256];
            kv = DECAY * kv + v;
            float key = fast_tanh(kv);
            kt = __builtin_fmaf(DECAY, kt, OMD * key);
            ko[(size_t)(t + j) * H] = key;
            c[(size_t)(t + j) * 256] = kt;
        }
    }
}

// 2 mem-rows per wave. CHAIN-SPLIT: iteration t computes A'=dot(mem_{t-1},k_{t+1})
// and B'=dot(w_t,k_{t+1}) + their reduces OFF the serial chain; the chain is only
// c -> fma -> tanh -> vt -> c. State nm = -mem. R10-verified swizzle reduce.
__global__ __launch_bounds__(256, 2) void value_scan(const float* __restrict__ keys,
                                                     const float* __restrict__ kts,
                                                     const float* __restrict__ iv_t,
                                                     float* __restrict__ mem_out,
                                                     float* __restrict__ vals) {
    const int tid  = threadIdx.x;
    const int wave = tid >> 6;
    const int lane = tid & 63;
    const int sub  = lane & 31;
    const int half = lane >> 5;
    const int b    = blockIdx.x & 15;     // XCD swizzle: batch-mates share an XCD
    const int rg   = blockIdx.x >> 4;
    const int row  = rg * 8 + wave * 2 + half;
    const int so   = sub * 8;

    const float* kp  = keys + (size_t)b * SS * H + so;
    const float* tp  = kts  + (size_t)b * SS * H + so;
    const float* ivp = iv_t + ((size_t)b * H + row) * SS;
    float* vrow = vals + (size_t)b * SS * H + row;

    v2f nm0 = {0.f,0.f}, nm1 = {0.f,0.f}, nm2 = {0.f,0.f}, nm3 = {0.f,0.f};
    v2f w0  = {0.f,0.f}, w1  = {0.f,0.f}, w2  = {0.f,0.f}, w3  = {0.f,0.f};
    float vv = 0.f, vt = 0.f, c = 0.f, ar = 0.f, br = 0.f, stash = 0.f;

    // rings: kR[j] holds the k_{t+1} stream (slot j init = k_{1+j}), tR[j] = kt_j
    v2f kR[8][4], tR[8][4];
#pragma unroll
    for (int j = 0; j < 8; ++j)
#pragma unroll
        for (int q = 0; q < 4; ++q) {
            kR[j][q] = *(const v2f*)(kp + (size_t)(1 + j) * H + q * 2);
            tR[j][q] = *(const v2f*)(tp + (size_t)j * H + q * 2);
        }
    const float* kpF = kp + 9 * H;   // reload target k_{t+9}
    const float* tpF = tp + 8 * H;   // reload target kt_{t+8}

    float4 iA0 = *(const float4*)(ivp + 0);
    float4 iA1 = *(const float4*)(ivp + 4);
    float4 iB0 = *(const float4*)(ivp + 8);
    float4 iB1 = *(const float4*)(ivp + 12);
    ivp += 16;

#define VS_STEP(J, RELK, RELT)                                                 \
    {                                                                          \
        v2f kc0 = kR[(J)&7][0], kc1 = kR[(J)&7][1],                            \
            kc2 = kR[(J)&7][2], kc3 = kR[(J)&7][3];                            \
        v2f tc0 = tR[(J)&7][0], tc1 = tR[(J)&7][1],                            \
            tc2 = tR[(J)&7][2], tc3 = tR[(J)&7][3];                            \
        if (RELK) {                                                            \
            kR[(J)&7][0] = *(const v2f*)(kpF + ((J)&3) * H + 0);               \
            kR[(J)&7][1] = *(const v2f*)(kpF + ((J)&3) * H + 2);               \
            kR[(J)&7][2] = *(const v2f*)(kpF + ((J)&3) * H + 4);               \
            kR[(J)&7][3] = *(const v2f*)(kpF + ((J)&3) * H + 6);               \
        }                                                                      \
        if (RELT) {                                                            \
            tR[(J)&7][0] = *(const v2f*)(tpF + ((J)&3) * H + 0);               \
            tR[(J)&7][1] = *(const v2f*)(tpF + ((J)&3) * H + 2);               \
            tR[(J)&7][2] = *(const v2f*)(tpF + ((J)&3) * H + 4);               \
            tR[(J)&7][3] = *(const v2f*)(tpF + ((J)&3) * H + 6);               \
        }                                                                      \
        /* ---- off-chain (uses c = c_{t-1}) ---- */                           \
        v2f nc2 = {-c, -c};                                                    \
        nm0 = pk_fma(nc2, w0, nm0);                                            \
        nm1 = pk_fma(nc2, w1, nm1);                                            \
        nm2 = pk_fma(nc2, w2, nm2);                                            \
        nm3 = pk_fma(nc2, w3, nm3);     /* nm = -mem_{t-1} */                  \
        v2f a2 = pk_mul(nm0, kc0);                                             \
        a2 = pk_fma(nm1, kc1, a2);                                             \
        a2 = pk_fma(nm2, kc2, a2);                                             \
        a2 = pk_fma(nm3, kc3, a2);      /* = -A'_{t+1} partial */              \
        w0 = pk_fma(tc0, nm0, tc0);                                            \
        w1 = pk_fma(tc1, nm1, tc1);                                            \
        w2 = pk_fma(tc2, nm2, tc2);                                            \
        w3 = pk_fma(tc3, nm3, tc3);     /* w_t = kt_t(1-mem_{t-1}) */          \
        v2f b2 = pk_mul(w0, kc0);                                              \
        b2 = pk_fma(w1, kc1, b2);                                              \
        b2 = pk_fma(w2, kc2, b2);                                              \
        b2 = pk_fma(w3, kc3, b2);       /* = B'_{t+1} partial */               \
        float arn = -0.2f * allred32(a2.x + a2.y);                             \
        float brn =  0.2f * allred32(b2.x + b2.y);                             \
        /* ---- chain: S_t folded in via ar,br from prev iter ---- */          \
        float vvt = __builtin_fmaf(DECAY, vv, ivs[J]) + ar;                    \
        vv = __builtin_fmaf(c, br, vvt);                                       \
        float valv = fast_tanh(vv);                                            \
        vt = __builtin_fmaf(DECAY, vt, OMD * valv);                            \
        if (sub == (J)) stash = valv;                                          \
        c = LR * vt;                                                           \
        ar = arn; br = brn;                                                    \
        asm volatile("" ::: "memory");                                         \
    }

    for (int t0 = 0; t0 < SS - 16; t0 += 16) {
        float4 nA0 = *(const float4*)(ivp + 0);
        float4 nA1 = *(const float4*)(ivp + 4);
        float4 nB0 = *(const float4*)(ivp + 8);
        float4 nB1 = *(const float4*)(ivp + 12);
        ivp += 16;
        {
            float ivs[16] = {iA0.x, iA0.y, iA0.z, iA0.w,
                             iA1.x, iA1.y, iA1.z, iA1.w,
                             iB0.x, iB0.y, iB0.z, iB0.w,
                             iB1.x, iB1.y, iB1.z, iB1.w};
            VS_STEP(0, 1, 1)  VS_STEP(1, 1, 1)  VS_STEP(2, 1, 1)  VS_STEP(3, 1, 1)
            kpF += 4 * H; tpF += 4 * H;
            VS_STEP(4, 1, 1)  VS_STEP(5, 1, 1)  VS_STEP(6, 1, 1)  VS_STEP(7, 1, 1)
            kpF += 4 * H; tpF += 4 * H;
            VS_STEP(8, 1, 1)  VS_STEP(9, 1, 1)  VS_STEP(10, 1, 1) VS_STEP(11, 1, 1)
            kpF += 4 * H; tpF += 4 * H;
            VS_STEP(12, 1, 1) VS_STEP(13, 1, 1) VS_STEP(14, 1, 1) VS_STEP(15, 1, 1)
            kpF += 4 * H; tpF += 4 * H;
        }
        if (sub < 16) vrow[(size_t)sub * H] = stash;
        vrow += 16 * H;
        iA0 = nA0; iA1 = nA1; iB0 = nB0; iB1 = nB1;
    }
    {   // final tile t0=496: k reload valid through J=6 (k_505..k_511);
        // J=7 reloads kt only (kt_511); J>=8 no reloads.
        float ivs[16] = {iA0.x, iA0.y, iA0.z, iA0.w,
                         iA1.x, iA1.y, iA1.z, iA1.w,
                         iB0.x, iB0.y, iB0.z, iB0.w,
                         iB1.x, iB1.y, iB1.z, iB1.w};
        VS_STEP(0, 1, 1)  VS_STEP(1, 1, 1)  VS_STEP(2, 1, 1)  VS_STEP(3, 1, 1)
        kpF += 4 * H; tpF += 4 * H;
        VS_STEP(4, 1, 1)  VS_STEP(5, 1, 1)  VS_STEP(6, 1, 1)  VS_STEP(7, 0, 1)
        VS_STEP(8, 0, 0)  VS_STEP(9, 0, 0)  VS_STEP(10, 0, 0) VS_STEP(11, 0, 0)
        VS_STEP(12, 0, 0) VS_STEP(13, 0, 0) VS_STEP(14, 0, 0) VS_STEP(15, 0, 0)
        if (sub < 16) vrow[(size_t)sub * H] = stash;
    }
#undef VS_STEP

    // final update: mem_511 = mem_510 + c_511 * w_511
    {
        v2f ncf = {-c, -c};
        nm0 = pk_fma(ncf, w0, nm0);
        nm1 = pk_fma(ncf, w1, nm1);
        nm2 = pk_fma(ncf, w2, nm2);
        nm3 = pk_fma(ncf, w3, nm3);
    }
    float* mo = &mem_out[((size_t)b * H + row) * H + so];
    *(float4*)&mo[0] = make_float4(-nm0.x, -nm0.y, -nm1.x, -nm1.y);
    *(float4*)&mo[4] = make_float4(-nm2.x, -nm2.y, -nm3.x, -nm3.y);
}

extern "C" void kernel_launch(void* const* d_in, const int* in_sizes, int n_in,
                              void* d_out, int out_size, void* d_ws, size_t ws_size,
                              hipStream_t stream) {
    const float* x = (const float*)d_in[0];   // [B, S, IN] f32
    const float* W = (const float*)d_in[1];   // [2H, IN] f32
    float* out = (float*)d_out;
    float* mem_out = out;                               // [B, H, H]
    float* keys = out + (size_t)BB * H * H;             // [B, S, H]
    float* vals = keys + (size_t)BB * SS * H;           // [B, S, H]
    float* ik   = (float*)d_ws;                         // [B*S, 256]  8 MB (becomes kt)
    float* iv_t = ik + (size_t)BB * SS * 256;           // [B, H, S]   8 MB

    dim3 gb(8, 128);  // N/64, M/64
    gemm_xwT<<<gb, 256, 0, stream>>>(x, W, ik, iv_t);
    key_scan<<<64, 64, 0, stream>>>(ik, keys);
    value_scan<<<512, 256, 0, stream>>>(keys, ik, iv_t, mem_out, vals);
}

// Round 13
// 264.093 us; speedup vs baseline: 1.2647x; 1.2647x over previous
//
#include <hip/hip_runtime.h>

#define BB 16
#define SS 512
#define KIN 512
#define H 256

typedef float v2f __attribute__((ext_vector_type(2)));

constexpr float DECAY = 0.951229424500714f;    // exp(-1/20), both tau=20
constexpr float OMD   = 0.048770575499286f;    // 1 - exp(-1/20)
constexpr float LR    = 0.01f;

__device__ __forceinline__ float fast_tanh(float x) {
    float e = __expf(2.f * x);
    return 1.f - __fdividef(2.f, e + 1.f);
}

__device__ __forceinline__ v2f pk_mul(v2f a, v2f b) {
    v2f d; asm("v_pk_mul_f32 %0, %1, %2" : "=v"(d) : "v"(a), "v"(b)); return d;
}
__device__ __forceinline__ v2f pk_fma(v2f a, v2f b, v2f c) {
    v2f d; asm("v_pk_fma_f32 %0, %1, %2, %3" : "=v"(d) : "v"(a), "v"(b), "v"(c)); return d;
}

// Per-32-half allreduce (R10-VERIFIED): 4x DPP row_shr prefix + row_bcast15
// (rows 1,3) puts half sums in lanes 31/63; ds_swizzle 0x3E0 (src = lane 31
// of each 32-group) broadcasts each half's own sum to all its lanes.
__device__ __forceinline__ float allred32(float x) {
    int t;
    t = __builtin_amdgcn_update_dpp(0, __float_as_int(x), 0x111, 0xf, 0xf, false);
    x += __int_as_float(t);
    t = __builtin_amdgcn_update_dpp(0, __float_as_int(x), 0x112, 0xf, 0xf, false);
    x += __int_as_float(t);
    t = __builtin_amdgcn_update_dpp(0, __float_as_int(x), 0x114, 0xf, 0xf, false);
    x += __int_as_float(t);
    t = __builtin_amdgcn_update_dpp(0, __float_as_int(x), 0x118, 0xf, 0xf, false);
    x += __int_as_float(t);
    t = __builtin_amdgcn_update_dpp(0, __float_as_int(x), 0x142, 0xa, 0xf, false);
    x += __int_as_float(t);
    return __int_as_float(__builtin_amdgcn_ds_swizzle(__float_as_int(x), 0x3E0));
}

// i = x @ W^T. ik half (n<256) -> ik_out[b*512+s][256]; iv half -> iv_t[b][row][s].
__global__ __launch_bounds__(256) void gemm_xwT(const float* __restrict__ X,
                                                const float* __restrict__ W,
                                                float* __restrict__ ik_out,
                                                float* __restrict__ iv_t) {
    __shared__ float As[16][68];
    __shared__ float Bs[16][68];
    const int m0 = blockIdx.y * 64;
    const int n0 = blockIdx.x * 64;
    const int tid = threadIdx.x;
    const int r  = tid >> 2;
    const int cg = tid & 3;
    const int tx = tid & 15;
    const int ty = tid >> 4;
    float acc[4][4] = {};
    for (int k0 = 0; k0 < KIN; k0 += 16) {
        float4 av = *(const float4*)&X[(size_t)(m0 + r) * KIN + k0 + cg * 4];
        float4 bv = *(const float4*)&W[(size_t)(n0 + r) * KIN + k0 + cg * 4];
        __syncthreads();
        As[cg*4+0][r] = av.x; As[cg*4+1][r] = av.y; As[cg*4+2][r] = av.z; As[cg*4+3][r] = av.w;
        Bs[cg*4+0][r] = bv.x; Bs[cg*4+1][r] = bv.y; Bs[cg*4+2][r] = bv.z; Bs[cg*4+3][r] = bv.w;
        __syncthreads();
#pragma unroll
        for (int kk = 0; kk < 16; ++kk) {
            float4 a = *(const float4*)&As[kk][ty * 4];
            float4 b = *(const float4*)&Bs[kk][tx * 4];
            float ar[4] = {a.x, a.y, a.z, a.w};
            float br[4] = {b.x, b.y, b.z, b.w};
#pragma unroll
            for (int i = 0; i < 4; ++i)
#pragma unroll
                for (int j = 0; j < 4; ++j) acc[i][j] += ar[i] * br[j];
        }
    }
    if (n0 < 256) {
#pragma unroll
        for (int i = 0; i < 4; ++i) {
            float4 o = make_float4(acc[i][0], acc[i][1], acc[i][2], acc[i][3]);
            *(float4*)&ik_out[(size_t)(m0 + ty * 4 + i) * 256 + n0 + tx * 4] = o;
        }
    } else {
        const int b  = m0 >> 9;
        const int s0 = (m0 & 511) + ty * 4;
#pragma unroll
        for (int j = 0; j < 4; ++j) {
            float4 o = make_float4(acc[0][j], acc[1][j], acc[2][j], acc[3][j]);
            *(float4*)&iv_t[((size_t)b * H + (n0 - 256 + tx * 4 + j)) * SS + s0] = o;
        }
    }
}

// Per (b, col): scan kv, write key only. 32-deep prefetch.
__global__ __launch_bounds__(64) void key_scan(const float* __restrict__ ik,
                                               float* __restrict__ keys) {
    const int idx = blockIdx.x * 64 + threadIdx.x;   // 0..4095
    const int b   = idx >> 8;
    const int col = idx & 255;
    const float* c  = ik + (size_t)b * SS * 256 + col;
    float* ko = keys + (size_t)b * SS * H + col;
    float kv = 0.f;
    constexpr int D = 32;
    float ib[D];
#pragma unroll
    for (int j = 0; j < D; ++j) ib[j] = c[(size_t)j * 256];
    for (int t = 0; t < SS; t += D) {
#pragma unroll
        for (int j = 0; j < D; ++j) {
            float v = ib[j];
            int tn = t + D + j; if (tn > SS - 1) tn = SS - 1;
            ib[j] = c[(size_t)tn * 256];
            kv = DECAY * kv + v;
            ko[(size_t)(t + j) * H] = fast_tanh(kv);
        }
    }
}

// 2 mem-rows per wave. CHAIN-SPLIT (R12 algebra, verified): at step t the
// off-chain part updates nm=-mem_{t-1}, computes kt_t in-register from the
// key consumed last step (kprev), forms w_t, dots both with k_{t+1} and
// reduces -> ar/br for step t+1. Chain is only c->fma->tanh->vt->c.
// Depth-4 key ring + in-register kt keeps live state ~115 VGPR (no spills).
__global__ __launch_bounds__(256, 2) void value_scan(const float* __restrict__ keys,
                                                     const float* __restrict__ iv_t,
                                                     float* __restrict__ mem_out,
                                                     float* __restrict__ vals) {
    const int tid  = threadIdx.x;
    const int wave = tid >> 6;
    const int lane = tid & 63;
    const int sub  = lane & 31;
    const int half = lane >> 5;
    const int b    = blockIdx.x & 15;     // XCD swizzle: batch-mates share an XCD
    const int rg   = blockIdx.x >> 4;
    const int row  = rg * 8 + wave * 2 + half;
    const int so   = sub * 8;

    const float* kp  = keys + (size_t)b * SS * H + so;
    const float* ivp = iv_t + ((size_t)b * H + row) * SS;
    float* vrow = vals + (size_t)b * SS * H + row;

    const v2f DEC2 = {DECAY, DECAY};
    const v2f OMD2 = {OMD, OMD};

    v2f nm0 = {0.f,0.f}, nm1 = {0.f,0.f}, nm2 = {0.f,0.f}, nm3 = {0.f,0.f};
    v2f w0  = {0.f,0.f}, w1  = {0.f,0.f}, w2  = {0.f,0.f}, w3  = {0.f,0.f};
    v2f kt0 = {0.f,0.f}, kt1 = {0.f,0.f}, kt2 = {0.f,0.f}, kt3 = {0.f,0.f};
    float vv = 0.f, vt = 0.f, c = 0.f, ar = 0.f, br = 0.f, stash = 0.f;

    // kprev = k_0 (own 8 columns); ring kR[j] = k_{1+j}, j=0..3
    v2f kp0 = *(const v2f*)(kp + 0), kp1 = *(const v2f*)(kp + 2),
        kp2 = *(const v2f*)(kp + 4), kp3 = *(const v2f*)(kp + 6);
    v2f kR[4][4];
#pragma unroll
    for (int j = 0; j < 4; ++j)
#pragma unroll
        for (int q = 0; q < 4; ++q)
            kR[j][q] = *(const v2f*)(kp + (size_t)(1 + j) * H + q * 2);
    const float* kpF = kp + 5 * H;   // reload target k_{t+5}

    float4 iA0 = *(const float4*)(ivp + 0);
    float4 iA1 = *(const float4*)(ivp + 4);
    float4 iB0 = *(const float4*)(ivp + 8);
    float4 iB1 = *(const float4*)(ivp + 12);
    ivp += 16;

#define VS_STEP(J, RELK)                                                       \
    {                                                                          \
        v2f kc0 = kR[(J)&3][0], kc1 = kR[(J)&3][1],                            \
            kc2 = kR[(J)&3][2], kc3 = kR[(J)&3][3];                            \
        if (RELK) {                                                            \
            kR[(J)&3][0] = *(const v2f*)(kpF + ((J)&3) * H + 0);               \
            kR[(J)&3][1] = *(const v2f*)(kpF + ((J)&3) * H + 2);               \
            kR[(J)&3][2] = *(const v2f*)(kpF + ((J)&3) * H + 4);               \
            kR[(J)&3][3] = *(const v2f*)(kpF + ((J)&3) * H + 6);               \
        }                                                                      \
        /* ---- off-chain (c = c_{t-1}) ---- */                                \
        v2f nc2 = {-c, -c};                                                    \
        nm0 = pk_fma(nc2, w0, nm0);                                            \
        nm1 = pk_fma(nc2, w1, nm1);                                            \
        nm2 = pk_fma(nc2, w2, nm2);                                            \
        nm3 = pk_fma(nc2, w3, nm3);        /* nm = -mem_{t-1} */               \
        kt0 = pk_fma(DEC2, kt0, pk_mul(OMD2, kp0));                            \
        kt1 = pk_fma(DEC2, kt1, pk_mul(OMD2, kp1));                            \
        kt2 = pk_fma(DEC2, kt2, pk_mul(OMD2, kp2));                            \
        kt3 = pk_fma(DEC2, kt3, pk_mul(OMD2, kp3));  /* kt_t (kprev=k_t) */    \
        w0 = pk_fma(kt0, nm0, kt0);                                            \
        w1 = pk_fma(kt1, nm1, kt1);                                            \
        w2 = pk_fma(kt2, nm2, kt2);                                            \
        w3 = pk_fma(kt3, nm3, kt3);        /* w_t = kt_t(1-mem_{t-1}) */       \
        v2f a2 = pk_mul(nm0, kc0);                                             \
        a2 = pk_fma(nm1, kc1, a2);                                             \
        a2 = pk_fma(nm2, kc2, a2);                                             \
        a2 = pk_fma(nm3, kc3, a2);         /* = -A_{t+1} partial */            \
        v2f b2 = pk_mul(w0, kc0);                                              \
        b2 = pk_fma(w1, kc1, b2);                                              \
        b2 = pk_fma(w2, kc2, b2);                                              \
        b2 = pk_fma(w3, kc3, b2);          /* = B_{t+1} partial */             \
        float arn = -0.2f * allred32(a2.x + a2.y);                             \
        float brn =  0.2f * allred32(b2.x + b2.y);                             \
        kp0 = kc0; kp1 = kc1; kp2 = kc2; kp3 = kc3;   /* kprev = k_{t+1} */    \
        /* ---- chain ---- */                                                  \
        float vvt = __builtin_fmaf(DECAY, vv, ivs[J]) + ar;                    \
        vv = __builtin_fmaf(c, br, vvt);                                       \
        float valv = fast_tanh(vv);                                            \
        vt = __builtin_fmaf(DECAY, vt, OMD * valv);                            \
        if (sub == (J)) stash = valv;                                          \
        c = LR * vt;                                                           \
        ar = arn; br = brn;                                                    \
        asm volatile("" ::: "memory");                                         \
    }

    for (int t0 = 0; t0 < SS - 16; t0 += 16) {
        float4 nA0 = *(const float4*)(ivp + 0);
        float4 nA1 = *(const float4*)(ivp + 4);
        float4 nB0 = *(const float4*)(ivp + 8);
        float4 nB1 = *(const float4*)(ivp + 12);
        ivp += 16;
        {
            float ivs[16] = {iA0.x, iA0.y, iA0.z, iA0.w,
                             iA1.x, iA1.y, iA1.z, iA1.w,
                             iB0.x, iB0.y, iB0.z, iB0.w,
                             iB1.x, iB1.y, iB1.z, iB1.w};
            VS_STEP(0, 1)  VS_STEP(1, 1)  VS_STEP(2, 1)  VS_STEP(3, 1)
            kpF += 4 * H;
            VS_STEP(4, 1)  VS_STEP(5, 1)  VS_STEP(6, 1)  VS_STEP(7, 1)
            kpF += 4 * H;
            VS_STEP(8, 1)  VS_STEP(9, 1)  VS_STEP(10, 1) VS_STEP(11, 1)
            kpF += 4 * H;
            VS_STEP(12, 1) VS_STEP(13, 1) VS_STEP(14, 1) VS_STEP(15, 1)
            kpF += 4 * H;
        }
        if (sub < 16) vrow[(size_t)sub * H] = stash;
        vrow += 16 * H;
        iA0 = nA0; iA1 = nA1; iB0 = nB0; iB1 = nB1;
    }
    {   // final tile t0=496: reload k_{t+5} valid for t<=506 (J<=10).
        // Steps 507-511 consume slots written at t=503..506 (k_508..k_511);
        // step 511's dot reads a stale slot -> feeds nonexistent step 512.
        float ivs[16] = {iA0.x, iA0.y, iA0.z, iA0.w,
                         iA1.x, iA1.y, iA1.z, iA1.w,
                         iB0.x, iB0.y, iB0.z, iB0.w,
                         iB1.x, iB1.y, iB1.z, iB1.w};
        VS_STEP(0, 1)  VS_STEP(1, 1)  VS_STEP(2, 1)  VS_STEP(3, 1)
        kpF += 4 * H;
        VS_STEP(4, 1)  VS_STEP(5, 1)  VS_STEP(6, 1)  VS_STEP(7, 1)
        kpF += 4 * H;
        VS_STEP(8, 1)  VS_STEP(9, 1)  VS_STEP(10, 1) VS_STEP(11, 0)
        VS_STEP(12, 0) VS_STEP(13, 0) VS_STEP(14, 0) VS_STEP(15, 0)
        if (sub < 16) vrow[(size_t)sub * H] = stash;
    }
#undef VS_STEP

    // final update: mem_511 = mem_510 + c_511 * w_511
    {
        v2f ncf = {-c, -c};
        nm0 = pk_fma(ncf, w0, nm0);
        nm1 = pk_fma(ncf, w1, nm1);
        nm2 = pk_fma(ncf, w2, nm2);
        nm3 = pk_fma(ncf, w3, nm3);
    }
    float* mo = &mem_out[((size_t)b * H + row) * H + so];
    *(float4*)&mo[0] = make_float4(-nm0.x, -nm0.y, -nm1.x, -nm1.y);
    *(float4*)&mo[4] = make_float4(-nm2.x, -nm2.y, -nm3.x, -nm3.y);
}

extern "C" void kernel_launch(void* const* d_in, const int* in_sizes, int n_in,
                              void* d_out, int out_size, void* d_ws, size_t ws_size,
                              hipStream_t stream) {
    const float* x = (const float*)d_in[0];   // [B, S, IN] f32
    const float* W = (const float*)d_in[1];   // [2H, IN] f32
    float* out = (float*)d_out;
    float* mem_out = out;                               // [B, H, H]
    float* keys = out + (size_t)BB * H * H;             // [B, S, H]
    float* vals = keys + (size_t)BB * SS * H;           // [B, S, H]
    float* ik   = (float*)d_ws;                         // [B*S, 256]  8 MB
    float* iv_t = ik + (size_t)BB * SS * 256;           // [B, H, S]   8 MB

    dim3 gb(8, 128);  // N/64, M/64
    gemm_xwT<<<gb, 256, 0, stream>>>(x, W, ik, iv_t);
    key_scan<<<64, 64, 0, stream>>>(ik, keys);
    value_scan<<<512, 256, 0, stream>>>(keys, iv_t, mem_out, vals);
}

// Round 14
// 243.548 us; speedup vs baseline: 1.3714x; 1.0844x over previous
//
#include <hip/hip_runtime.h>

#define BB 16
#define SS 512
#define KIN 512
#define H 256

typedef float v2f __attribute__((ext_vector_type(2)));

constexpr float DECAY   = 0.951229424500714f;    // exp(-1/20), both tau=20
constexpr float OMD     = 0.048770575499286f;    // 1 - exp(-1/20)
constexpr float DECAY64 = 0.040762203978366f;    // exp(-64/20)
constexpr float LR      = 0.01f;

__device__ __forceinline__ float fast_tanh(float x) {
    float e = __expf(2.f * x);
    return 1.f - __fdividef(2.f, e + 1.f);
}

__device__ __forceinline__ v2f pk_mul(v2f a, v2f b) {
    v2f d; asm("v_pk_mul_f32 %0, %1, %2" : "=v"(d) : "v"(a), "v"(b)); return d;
}
__device__ __forceinline__ v2f pk_fma(v2f a, v2f b, v2f c) {
    v2f d; asm("v_pk_fma_f32 %0, %1, %2, %3" : "=v"(d) : "v"(a), "v"(b), "v"(c)); return d;
}

// Per-32-half allreduce (R10-VERIFIED): DPP prefix + row_bcast15 + ds_swizzle
// 0x3E0 broadcast of lane31/63 to each 32-half.
__device__ __forceinline__ float allred32(float x) {
    int t;
    t = __builtin_amdgcn_update_dpp(0, __float_as_int(x), 0x111, 0xf, 0xf, false);
    x += __int_as_float(t);
    t = __builtin_amdgcn_update_dpp(0, __float_as_int(x), 0x112, 0xf, 0xf, false);
    x += __int_as_float(t);
    t = __builtin_amdgcn_update_dpp(0, __float_as_int(x), 0x114, 0xf, 0xf, false);
    x += __int_as_float(t);
    t = __builtin_amdgcn_update_dpp(0, __float_as_int(x), 0x118, 0xf, 0xf, false);
    x += __int_as_float(t);
    t = __builtin_amdgcn_update_dpp(0, __float_as_int(x), 0x142, 0xa, 0xf, false);
    x += __int_as_float(t);
    return __int_as_float(__builtin_amdgcn_ds_swizzle(__float_as_int(x), 0x3E0));
}

// i = x @ W^T. ik half (n<256) -> ik_out[b*512+s][256]; iv half -> iv_t[b][row][s].
__global__ __launch_bounds__(256) void gemm_xwT(const float* __restrict__ X,
                                                const float* __restrict__ W,
                                                float* __restrict__ ik_out,
                                                float* __restrict__ iv_t) {
    __shared__ float As[16][68];
    __shared__ float Bs[16][68];
    const int m0 = blockIdx.y * 64;
    const int n0 = blockIdx.x * 64;
    const int tid = threadIdx.x;
    const int r  = tid >> 2;
    const int cg = tid & 3;
    const int tx = tid & 15;
    const int ty = tid >> 4;
    float acc[4][4] = {};
    for (int k0 = 0; k0 < KIN; k0 += 16) {
        float4 av = *(const float4*)&X[(size_t)(m0 + r) * KIN + k0 + cg * 4];
        float4 bv = *(const float4*)&W[(size_t)(n0 + r) * KIN + k0 + cg * 4];
        __syncthreads();
        As[cg*4+0][r] = av.x; As[cg*4+1][r] = av.y; As[cg*4+2][r] = av.z; As[cg*4+3][r] = av.w;
        Bs[cg*4+0][r] = bv.x; Bs[cg*4+1][r] = bv.y; Bs[cg*4+2][r] = bv.z; Bs[cg*4+3][r] = bv.w;
        __syncthreads();
#pragma unroll
        for (int kk = 0; kk < 16; ++kk) {
            float4 a = *(const float4*)&As[kk][ty * 4];
            float4 b = *(const float4*)&Bs[kk][tx * 4];
            float ar[4] = {a.x, a.y, a.z, a.w};
            float br[4] = {b.x, b.y, b.z, b.w};
#pragma unroll
            for (int i = 0; i < 4; ++i)
#pragma unroll
                for (int j = 0; j < 4; ++j) acc[i][j] += ar[i] * br[j];
        }
    }
    if (n0 < 256) {
#pragma unroll
        for (int i = 0; i < 4; ++i) {
            float4 o = make_float4(acc[i][0], acc[i][1], acc[i][2], acc[i][3]);
            *(float4*)&ik_out[(size_t)(m0 + ty * 4 + i) * 256 + n0 + tx * 4] = o;
        }
    } else {
        const int b  = m0 >> 9;
        const int s0 = (m0 & 511) + ty * 4;
#pragma unroll
        for (int j = 0; j < 4; ++j) {
            float4 o = make_float4(acc[0][j], acc[1][j], acc[2][j], acc[3][j]);
            *(float4*)&iv_t[((size_t)b * H + (n0 - 256 + tx * 4 + j)) * SS + s0] = o;
        }
    }
}

// ---- parallel key scan (kv is linear in ik): 3 phases, 8 chunks of 64 ----

// Phase 1: E[b][chunk][col] = sum_{j<64} DECAY^(63-j) * ik[b][chunk*64+j][col]
__global__ __launch_bounds__(256) void ks1_chunk(const float* __restrict__ ik,
                                                 float* __restrict__ E) {
    const int tid  = blockIdx.x * 256 + threadIdx.x;   // 0..32767
    const int col  = tid & 255;
    const int rest = tid >> 8;      // 0..127
    const int b    = rest >> 3;
    const int ch   = rest & 7;
    const float* p = ik + ((size_t)(b * SS + ch * 64)) * 256 + col;
    float e = 0.f;
    float rb[4];
#pragma unroll
    for (int j = 0; j < 4; ++j) rb[j] = p[(size_t)j * 256];
    for (int j0 = 0; j0 < 64; j0 += 4) {
#pragma unroll
        for (int j = 0; j < 4; ++j) {
            float v = rb[j];
            int jn = j0 + 4 + j; if (jn > 63) jn = 63;
            rb[j] = p[(size_t)jn * 256];
            e = __builtin_fmaf(DECAY, e, v);
        }
    }
    E[((size_t)b * 8 + ch) * 256 + col] = e;
}

// Phase 2: per (b,col): Sst[b][c][col] = kv value entering chunk c.
__global__ __launch_bounds__(64) void ks2_carry(const float* __restrict__ E,
                                                float* __restrict__ Sst) {
    const int idx = blockIdx.x * 64 + threadIdx.x;   // 0..4095
    const int b   = idx >> 8;
    const int col = idx & 255;
    float carry = 0.f;
#pragma unroll
    for (int c = 0; c < 8; ++c) {
        Sst[((size_t)b * 8 + c) * 256 + col] = carry;
        carry = __builtin_fmaf(DECAY64, carry, E[((size_t)b * 8 + c) * 256 + col]);
    }
}

// Phase 3: re-scan each chunk from its carry, emit key = tanh(kv).
__global__ __launch_bounds__(256) void ks3_emit(const float* __restrict__ ik,
                                                const float* __restrict__ Sst,
                                                float* __restrict__ keys) {
    const int tid  = blockIdx.x * 256 + threadIdx.x;   // 0..32767
    const int col  = tid & 255;
    const int rest = tid >> 8;
    const int b    = rest >> 3;
    const int ch   = rest & 7;
    const float* p = ik + ((size_t)(b * SS + ch * 64)) * 256 + col;
    float* ko = keys + ((size_t)(b * SS + ch * 64)) * H + col;
    float kv = Sst[((size_t)b * 8 + ch) * 256 + col];
    float rb[4];
#pragma unroll
    for (int j = 0; j < 4; ++j) rb[j] = p[(size_t)j * 256];
    for (int j0 = 0; j0 < 64; j0 += 4) {
#pragma unroll
        for (int j = 0; j < 4; ++j) {
            float v = rb[j];
            int jn = j0 + 4 + j; if (jn > 63) jn = 63;
            rb[j] = p[(size_t)jn * 256];
            kv = __builtin_fmaf(DECAY, kv, v);
            ko[(size_t)(j0 + j) * H] = fast_tanh(kv);
        }
    }
}

// value_scan: byte-identical to R13 (verified, 165 us).
__global__ __launch_bounds__(256, 2) void value_scan(const float* __restrict__ keys,
                                                     const float* __restrict__ iv_t,
                                                     float* __restrict__ mem_out,
                                                     float* __restrict__ vals) {
    const int tid  = threadIdx.x;
    const int wave = tid >> 6;
    const int lane = tid & 63;
    const int sub  = lane & 31;
    const int half = lane >> 5;
    const int b    = blockIdx.x & 15;
    const int rg   = blockIdx.x >> 4;
    const int row  = rg * 8 + wave * 2 + half;
    const int so   = sub * 8;

    const float* kp  = keys + (size_t)b * SS * H + so;
    const float* ivp = iv_t + ((size_t)b * H + row) * SS;
    float* vrow = vals + (size_t)b * SS * H + row;

    const v2f DEC2 = {DECAY, DECAY};
    const v2f OMD2 = {OMD, OMD};

    v2f nm0 = {0.f,0.f}, nm1 = {0.f,0.f}, nm2 = {0.f,0.f}, nm3 = {0.f,0.f};
    v2f w0  = {0.f,0.f}, w1  = {0.f,0.f}, w2  = {0.f,0.f}, w3  = {0.f,0.f};
    v2f kt0 = {0.f,0.f}, kt1 = {0.f,0.f}, kt2 = {0.f,0.f}, kt3 = {0.f,0.f};
    float vv = 0.f, vt = 0.f, c = 0.f, ar = 0.f, br = 0.f, stash = 0.f;

    v2f kp0 = *(const v2f*)(kp + 0), kp1 = *(const v2f*)(kp + 2),
        kp2 = *(const v2f*)(kp + 4), kp3 = *(const v2f*)(kp + 6);
    v2f kR[4][4];
#pragma unroll
    for (int j = 0; j < 4; ++j)
#pragma unroll
        for (int q = 0; q < 4; ++q)
            kR[j][q] = *(const v2f*)(kp + (size_t)(1 + j) * H + q * 2);
    const float* kpF = kp + 5 * H;

    float4 iA0 = *(const float4*)(ivp + 0);
    float4 iA1 = *(const float4*)(ivp + 4);
    float4 iB0 = *(const float4*)(ivp + 8);
    float4 iB1 = *(const float4*)(ivp + 12);
    ivp += 16;

#define VS_STEP(J, RELK)                                                       \
    {                                                                          \
        v2f kc0 = kR[(J)&3][0], kc1 = kR[(J)&3][1],                            \
            kc2 = kR[(J)&3][2], kc3 = kR[(J)&3][3];                            \
        if (RELK) {                                                            \
            kR[(J)&3][0] = *(const v2f*)(kpF + ((J)&3) * H + 0);               \
            kR[(J)&3][1] = *(const v2f*)(kpF + ((J)&3) * H + 2);               \
            kR[(J)&3][2] = *(const v2f*)(kpF + ((J)&3) * H + 4);               \
            kR[(J)&3][3] = *(const v2f*)(kpF + ((J)&3) * H + 6);               \
        }                                                                      \
        v2f nc2 = {-c, -c};                                                    \
        nm0 = pk_fma(nc2, w0, nm0);                                            \
        nm1 = pk_fma(nc2, w1, nm1);                                            \
        nm2 = pk_fma(nc2, w2, nm2);                                            \
        nm3 = pk_fma(nc2, w3, nm3);                                            \
        kt0 = pk_fma(DEC2, kt0, pk_mul(OMD2, kp0));                            \
        kt1 = pk_fma(DEC2, kt1, pk_mul(OMD2, kp1));                            \
        kt2 = pk_fma(DEC2, kt2, pk_mul(OMD2, kp2));                            \
        kt3 = pk_fma(DEC2, kt3, pk_mul(OMD2, kp3));                            \
        w0 = pk_fma(kt0, nm0, kt0);                                            \
        w1 = pk_fma(kt1, nm1, kt1);                                            \
        w2 = pk_fma(kt2, nm2, kt2);                                            \
        w3 = pk_fma(kt3, nm3, kt3);                                            \
        v2f a2 = pk_mul(nm0, kc0);                                             \
        a2 = pk_fma(nm1, kc1, a2);                                             \
        a2 = pk_fma(nm2, kc2, a2);                                             \
        a2 = pk_fma(nm3, kc3, a2);                                             \
        v2f b2 = pk_mul(w0, kc0);                                              \
        b2 = pk_fma(w1, kc1, b2);                                              \
        b2 = pk_fma(w2, kc2, b2);                                              \
        b2 = pk_fma(w3, kc3, b2);                                              \
        float arn = -0.2f * allred32(a2.x + a2.y);                             \
        float brn =  0.2f * allred32(b2.x + b2.y);                             \
        kp0 = kc0; kp1 = kc1; kp2 = kc2; kp3 = kc3;                            \
        float vvt = __builtin_fmaf(DECAY, vv, ivs[J]) + ar;                    \
        vv = __builtin_fmaf(c, br, vvt);                                       \
        float valv = fast_tanh(vv);                                            \
        vt = __builtin_fmaf(DECAY, vt, OMD * valv);                            \
        if (sub == (J)) stash = valv;                                          \
        c = LR * vt;                                                           \
        ar = arn; br = brn;                                                    \
        asm volatile("" ::: "memory");                                         \
    }

    for (int t0 = 0; t0 < SS - 16; t0 += 16) {
        float4 nA0 = *(const float4*)(ivp + 0);
        float4 nA1 = *(const float4*)(ivp + 4);
        float4 nB0 = *(const float4*)(ivp + 8);
        float4 nB1 = *(const float4*)(ivp + 12);
        ivp += 16;
        {
            float ivs[16] = {iA0.x, iA0.y, iA0.z, iA0.w,
                             iA1.x, iA1.y, iA1.z, iA1.w,
                             iB0.x, iB0.y, iB0.z, iB0.w,
                             iB1.x, iB1.y, iB1.z, iB1.w};
            VS_STEP(0, 1)  VS_STEP(1, 1)  VS_STEP(2, 1)  VS_STEP(3, 1)
            kpF += 4 * H;
            VS_STEP(4, 1)  VS_STEP(5, 1)  VS_STEP(6, 1)  VS_STEP(7, 1)
            kpF += 4 * H;
            VS_STEP(8, 1)  VS_STEP(9, 1)  VS_STEP(10, 1) VS_STEP(11, 1)
            kpF += 4 * H;
            VS_STEP(12, 1) VS_STEP(13, 1) VS_STEP(14, 1) VS_STEP(15, 1)
            kpF += 4 * H;
        }
        if (sub < 16) vrow[(size_t)sub * H] = stash;
        vrow += 16 * H;
        iA0 = nA0; iA1 = nA1; iB0 = nB0; iB1 = nB1;
    }
    {
        float ivs[16] = {iA0.x, iA0.y, iA0.z, iA0.w,
                         iA1.x, iA1.y, iA1.z, iA1.w,
                         iB0.x, iB0.y, iB0.z, iB0.w,
                         iB1.x, iB1.y, iB1.z, iB1.w};
        VS_STEP(0, 1)  VS_STEP(1, 1)  VS_STEP(2, 1)  VS_STEP(3, 1)
        kpF += 4 * H;
        VS_STEP(4, 1)  VS_STEP(5, 1)  VS_STEP(6, 1)  VS_STEP(7, 1)
        kpF += 4 * H;
        VS_STEP(8, 1)  VS_STEP(9, 1)  VS_STEP(10, 1) VS_STEP(11, 0)
        VS_STEP(12, 0) VS_STEP(13, 0) VS_STEP(14, 0) VS_STEP(15, 0)
        if (sub < 16) vrow[(size_t)sub * H] = stash;
    }
#undef VS_STEP

    {
        v2f ncf = {-c, -c};
        nm0 = pk_fma(ncf, w0, nm0);
        nm1 = pk_fma(ncf, w1, nm1);
        nm2 = pk_fma(ncf, w2, nm2);
        nm3 = pk_fma(ncf, w3, nm3);
    }
    float* mo = &mem_out[((size_t)b * H + row) * H + so];
    *(float4*)&mo[0] = make_float4(-nm0.x, -nm0.y, -nm1.x, -nm1.y);
    *(float4*)&mo[4] = make_float4(-nm2.x, -nm2.y, -nm3.x, -nm3.y);
}

extern "C" void kernel_launch(void* const* d_in, const int* in_sizes, int n_in,
                              void* d_out, int out_size, void* d_ws, size_t ws_size,
                              hipStream_t stream) {
    const float* x = (const float*)d_in[0];   // [B, S, IN] f32
    const float* W = (const float*)d_in[1];   // [2H, IN] f32
    float* out = (float*)d_out;
    float* mem_out = out;                               // [B, H, H]
    float* keys = out + (size_t)BB * H * H;             // [B, S, H]
    float* vals = keys + (size_t)BB * SS * H;           // [B, S, H]
    float* ik   = (float*)d_ws;                         // [B*S, 256]  8 MB
    float* iv_t = ik + (size_t)BB * SS * 256;           // [B, H, S]   8 MB
    // E/Sst scratch (32k floats each) lives in vals, fully overwritten later.
    float* E    = vals;
    float* Sst  = vals + 32768;

    dim3 gb(8, 128);  // N/64, M/64
    gemm_xwT<<<gb, 256, 0, stream>>>(x, W, ik, iv_t);
    ks1_chunk<<<128, 256, 0, stream>>>(ik, E);
    ks2_carry<<<64, 64, 0, stream>>>(E, Sst);
    ks3_emit<<<128, 256, 0, stream>>>(ik, Sst, keys);
    value_scan<<<512, 256, 0, stream>>>(keys, iv_t, mem_out, vals);
}